// Round 1
// baseline (875.415 us; speedup 1.0000x reference)
//
#include <hip/hip_runtime.h>
#include <stdint.h>

// Problem constants
#define B_SZ 2048
#define N_SZ 512
#define H_SZ 20
#define T_STEPS 3

typedef unsigned short u16;
typedef __attribute__((ext_vector_type(8))) short bf8;   // 8 bf16 (4 VGPRs)
typedef __attribute__((ext_vector_type(4))) float f4;    // MFMA 16x16 accumulator

#define MFMA(a, b, c) __builtin_amdgcn_mfma_f32_16x16x32_bf16((a), (b), (c), 0, 0, 0)

__device__ __forceinline__ u16 f2bf(float f) {
    union { float f; uint32_t u; } v; v.f = f;
    uint32_t u = v.u;
    u += 0x7FFFu + ((u >> 16) & 1u);   // RNE
    return (u16)(u >> 16);
}
__device__ __forceinline__ float bf2f(u16 h) {
    union { uint32_t u; float f; } v; v.u = ((uint32_t)h) << 16;
    return v.f;
}
// scratch2 addressing: [c (32 cols)][fblock^swizzle (8)][8], bf16 elements
__device__ __forceinline__ int scoff(int c, int f) {
    return c * 64 + (((f >> 3) ^ (c & 7)) << 3) + (f & 7);
}
__device__ __forceinline__ float sigm(float x) { return 1.f / (1.f + __expf(-x)); }

// ---------------- prep kernels ----------------

// x [B][N][H] f32  ->  nodes [B][H][N] bf16   (one block per batch)
__global__ void prep_nodes(const float* __restrict__ x, u16* __restrict__ nodes) {
    __shared__ float xt[N_SZ * H_SZ];
    int b = blockIdx.x;
    const float* xb = x + (size_t)b * N_SZ * H_SZ;
    for (int i = threadIdx.x; i < N_SZ * H_SZ; i += 256) xt[i] = xb[i];
    __syncthreads();
    u16* nb = nodes + (size_t)b * H_SZ * N_SZ;
    for (int i = threadIdx.x; i < H_SZ * N_SZ; i += 256) {
        int h = i / N_SZ, m = i - h * N_SZ;
        nb[i] = f2bf(xt[m * H_SZ + h]);
    }
}

// xo [B][N][H] bf16 = x @ W_out[:,H:].T + b_out  (thread per (b,n))
__global__ void prep_xo(const float* __restrict__ x, const float* __restrict__ Wout,
                        const float* __restrict__ bout, u16* __restrict__ xo) {
    int i = blockIdx.x * 256 + threadIdx.x;      // (b*N+n)
    const float* xv = x + (size_t)i * H_SZ;
    float xl[H_SZ];
    #pragma unroll
    for (int h = 0; h < H_SZ; h++) xl[h] = xv[h];
    u16* o = xo + (size_t)i * H_SZ;
    for (int hp = 0; hp < H_SZ; hp++) {
        float s = bout[hp];
        const float* wr = Wout + hp * 2 * H_SZ + H_SZ;
        #pragma unroll
        for (int h = 0; h < H_SZ; h++) s += xl[h] * wr[h];
        o[hp] = f2bf(s);
    }
}

// A fragment tables: pAT[nt][kt][lane][8] = A[n][m] (B-op for agg_in),
//                    pA [nt][kt][lane][8] = A[m][n] (B-op for agg_out)
__global__ void prep_afrag(const float* __restrict__ A, u16* __restrict__ pAT,
                           u16* __restrict__ pA) {
    int idx = blockIdx.x * 256 + threadIdx.x;    // (nt*16 + kt)*64 + lane
    int lane = idx & 63;
    int kt = (idx >> 6) & 15;
    int nt = idx >> 10;
    int n = nt * 16 + (lane & 15);
    int k0 = kt * 32 + (lane >> 4) * 8;
    u16* d1 = pAT + (size_t)idx * 8;
    u16* d2 = pA + (size_t)idx * 8;
    #pragma unroll
    for (int j = 0; j < 8; j++) {
        int m = k0 + j;
        d1[j] = f2bf(A[(size_t)n * N_SZ + m]);
        d2[j] = f2bf(A[(size_t)m * N_SZ + n]);
    }
}

// Gate weight fragment tables.
// wbig: M=96 (rows 0-19 z | 32-51 r | 64-83 h-av; zero pad), K=64
//       (k 0-39: W*w over [agg_in,agg_out]; k 40-59: W*u over fn (zero for h); 60-63 zero)
// whu : M=32 K=32 : W5u zero-padded
// wo1 : M=32 K=32 : W_out[:, :H] zero-padded
__global__ void prep_wfrag(const float* __restrict__ W3w, const float* __restrict__ W3u,
                           const float* __restrict__ W4w, const float* __restrict__ W4u,
                           const float* __restrict__ W5w, const float* __restrict__ W5u,
                           const float* __restrict__ Wout,
                           u16* __restrict__ wbig, u16* __restrict__ whu, u16* __restrict__ wo1) {
    int t = blockIdx.x * 256 + threadIdx.x;      // 0..1023
    int lane = t & 63;
    int l16 = lane & 15, quad = lane >> 4;
    if (t < 768) {
        int kt = (t >> 6) & 1;
        int mt = t >> 7;
        int mrow = mt * 16 + l16;
        int g = mrow >> 5, lr = mrow & 31;
        u16* d = wbig + (size_t)t * 8;
        #pragma unroll
        for (int j = 0; j < 8; j++) {
            int k = kt * 32 + quad * 8 + j;
            float v = 0.f;
            if (lr < 20) {
                if (k < 40) {
                    const float* W = (g == 0) ? W3w : (g == 1) ? W4w : W5w;
                    v = W[lr * 40 + k];
                } else if (k < 60 && g < 2) {
                    const float* U = (g == 0) ? W3u : W4u;
                    v = U[lr * 20 + (k - 40)];
                }
            }
            d[j] = f2bf(v);
        }
    } else if (t < 896) {
        int tt = t - 768;
        int mrow = (tt >> 6) * 16 + l16;
        u16* d = whu + (size_t)tt * 8;
        #pragma unroll
        for (int j = 0; j < 8; j++) {
            int k = quad * 8 + j;
            d[j] = f2bf((mrow < 20 && k < 20) ? W5u[mrow * 20 + k] : 0.f);
        }
    } else {
        int tt = t - 896;
        int mrow = (tt >> 6) * 16 + l16;
        u16* d = wo1 + (size_t)tt * 8;
        #pragma unroll
        for (int j = 0; j < 8; j++) {
            int k = quad * 8 + j;
            d[j] = f2bf((mrow < 20 && k < 20) ? Wout[mrow * 40 + k] : 0.f);
        }
    }
}

__global__ void ws_too_small(float* out) { out[0] = 12345.0f; }

// ---------------- per-step fused kernel ----------------
// One workgroup = 2 batches. LDS: Xs[40 rows (b,h)][512 m] bf16 XOR-swizzled
// + per-wave scratch2 (32 cols x 64 feats, swizzled).
__global__ __launch_bounds__(256, 2)
void step_kernel(const u16* __restrict__ pAT, const u16* __restrict__ pA,
                 const u16* __restrict__ wbig, const u16* __restrict__ whu,
                 const u16* __restrict__ wo1, const u16* __restrict__ xo,
                 u16* __restrict__ nodes, float* __restrict__ out, int t_step)
{
    __shared__ __align__(16) u16 lds_all[40 * 512 + 4 * 2048];   // Xs | sc2, 57344 B
    u16* Xs = lds_all;
    int tid = threadIdx.x;
    int wv = tid >> 6, lane = tid & 63;
    int l16 = lane & 15, quad = lane >> 4;
    int b0 = blockIdx.x * 2;
    u16* scw = lds_all + 40 * 512 + wv * 2048;

    // ---- phase 1: stage nodes[b0..b0+1] -> Xs (swizzled) ----
    const u16* nb = nodes + (size_t)b0 * (H_SZ * N_SZ);
    #pragma unroll
    for (int i = 0; i < 10; i++) {
        int blk = i * 256 + tid;           // 0..2559 : row(40) x mblk(64)
        int row = blk >> 6, mblk = blk & 63;
        uint4 v = *(const uint4*)(nb + (size_t)row * 512 + mblk * 8);
        *(uint4*)&Xs[row * 512 + ((mblk ^ (row & 7)) << 3)] = v;
    }
    __syncthreads();
    // From here waves are fully independent (own n-tiles, own scratch).

    for (int p = 0; p < 4; p++) {
        int nt0 = wv * 8 + p * 2;

        // ---- phase 2: aggregation GEMM for an n-tile pair ----
        f4 acc[2][3][2];                    // [ntL][mt][agg]
        #pragma unroll
        for (int a0 = 0; a0 < 2; a0++)
            #pragma unroll
            for (int a1 = 0; a1 < 3; a1++)
                #pragma unroll
                for (int a2 = 0; a2 < 2; a2++)
                    acc[a0][a1][a2] = (f4){0.f, 0.f, 0.f, 0.f};

        for (int kt = 0; kt < 16; kt++) {
            bf8 af[3];
            #pragma unroll
            for (int mt = 0; mt < 3; mt++) {
                int row = mt * 16 + l16;                       // rows 40-47 read junk; C rows ignored
                int kb = (kt * 4 + quad) ^ (row & 7);
                af[mt] = *(const bf8*)&Xs[row * 512 + kb * 8];
            }
            #pragma unroll
            for (int ntL = 0; ntL < 2; ntL++) {
                size_t fo = ((size_t)((nt0 + ntL) * 16 + kt) * 64 + lane) * 8;
                bf8 bi = *(const bf8*)(pAT + fo);
                bf8 bo = *(const bf8*)(pA + fo);
                #pragma unroll
                for (int mt = 0; mt < 3; mt++) {
                    acc[ntL][mt][0] = MFMA(af[mt], bi, acc[ntL][mt][0]);
                    acc[ntL][mt][1] = MFMA(af[mt], bo, acc[ntL][mt][1]);
                }
            }
        }

        // ---- phase 3: gates + update + output, per n-tile ----
        #pragma unroll
        for (int ntL = 0; ntL < 2; ntL++) {
            int nt = nt0 + ntL;
            int nglob = nt * 16 + l16;

            // 3a: agg C-tiles -> scratch2 feats 0..39 (f = agg*20+h, c = bsub*16+n_local)
            #pragma unroll
            for (int mt = 0; mt < 3; mt++) {
                if (mt < 2 || quad < 2) {
                    int row0 = mt * 16 + quad * 4;              // 4-aligned; 20-boundary safe
                    int bs = (row0 >= 20) ? 1 : 0;
                    int h0 = row0 - bs * 20;
                    int c = bs * 16 + l16;
                    #pragma unroll
                    for (int r = 0; r < 4; r++) {
                        scw[scoff(c, h0 + r)]      = f2bf(acc[ntL][mt][0][r]);
                        scw[scoff(c, 20 + h0 + r)] = f2bf(acc[ntL][mt][1][r]);
                    }
                }
            }
            // 3a2: fn -> feats 40..59 ; zero feats 60..63 (avoid NaN garbage into MFMA)
            {
                int c = lane & 31;
                int h0 = (lane >> 5) * 10;
                int bs = c >> 4, nl = c & 15;
                int m = nt * 16 + nl;
                int mb = m >> 3, mo = m & 7;
                #pragma unroll
                for (int i = 0; i < 10; i++) {
                    int h = h0 + i;
                    int row = bs * 20 + h;
                    u16 v = Xs[row * 512 + ((mb ^ (row & 7)) << 3) + mo];
                    scw[scoff(c, 40 + h)] = v;
                }
                if (lane < 32) {
                    #pragma unroll
                    for (int f = 60; f < 64; f++) scw[scoff(c, f)] = 0;
                }
            }

            // 3b: G1 = Wbig(96x64) @ scratch2(64x32): z|r|h_av pre-activations
            f4 g1[6][2];
            #pragma unroll
            for (int a0 = 0; a0 < 6; a0++) { g1[a0][0] = (f4){0,0,0,0}; g1[a0][1] = (f4){0,0,0,0}; }
            #pragma unroll
            for (int kt = 0; kt < 2; kt++) {
                bf8 bfr[2];
                #pragma unroll
                for (int ct = 0; ct < 2; ct++) {
                    int c = ct * 16 + l16;
                    int fb = (kt * 4 + quad) ^ (c & 7);
                    bfr[ct] = *(const bf8*)&scw[c * 64 + fb * 8];
                }
                #pragma unroll
                for (int mt = 0; mt < 6; mt++) {
                    bf8 wf = *(const bf8*)(wbig + ((size_t)(mt * 2 + kt) * 64 + lane) * 8);
                    g1[mt][0] = MFMA(wf, bfr[0], g1[mt][0]);
                    g1[mt][1] = MFMA(wf, bfr[1], g1[mt][1]);
                }
            }

            // 3c: rp = sigmoid(r)*fn -> feats 0..19 (agg_in slots are dead)
            #pragma unroll
            for (int ct = 0; ct < 2; ct++) {
                int c = ct * 16 + l16;
                #pragma unroll
                for (int r = 0; r < 4; r++) {
                    int hp = quad * 4 + r;
                    float fn = bf2f(scw[scoff(c, 40 + hp)]);
                    scw[scoff(c, hp)] = f2bf(sigm(g1[2][ct][r]) * fn);
                }
                if (quad == 0) {
                    #pragma unroll
                    for (int r = 0; r < 4; r++) {
                        int hp = 16 + r;
                        float fn = bf2f(scw[scoff(c, 40 + hp)]);
                        scw[scoff(c, hp)] = f2bf(sigm(g1[3][ct][r]) * fn);
                    }
                }
            }

            // 3d: hu = W5u_pad(32x32) @ rp
            f4 hu[2][2];
            hu[0][0] = (f4){0,0,0,0}; hu[0][1] = (f4){0,0,0,0};
            hu[1][0] = (f4){0,0,0,0}; hu[1][1] = (f4){0,0,0,0};
            #pragma unroll
            for (int ct = 0; ct < 2; ct++) {
                int c = ct * 16 + l16;
                int fb = quad ^ (c & 7);
                bf8 bfr = *(const bf8*)&scw[c * 64 + fb * 8];
                #pragma unroll
                for (int mt = 0; mt < 2; mt++) {
                    bf8 wf = *(const bf8*)(whu + ((size_t)(mt * 64) + lane) * 8);
                    hu[mt][ct] = MFMA(wf, bfr, hu[mt][ct]);
                }
            }

            // 3e: fn_new = (1-z)*fn + z*tanh(h_av + hu); write nodes + feats 0..19
            #pragma unroll
            for (int ct = 0; ct < 2; ct++) {
                int c = ct * 16 + l16;
                size_t nbase = ((size_t)(b0 + ct) * H_SZ) * N_SZ + nglob;
                #pragma unroll
                for (int r = 0; r < 4; r++) {
                    int hp = quad * 4 + r;
                    float fn = bf2f(scw[scoff(c, 40 + hp)]);
                    float z = sigm(g1[0][ct][r]);
                    float hpre = g1[4][ct][r] + hu[0][ct][r];
                    float hv = 2.f / (1.f + __expf(-2.f * hpre)) - 1.f;
                    u16 w = f2bf((1.f - z) * fn + z * hv);
                    nodes[nbase + (size_t)hp * N_SZ] = w;
                    scw[scoff(c, hp)] = w;
                }
                if (quad == 0) {
                    #pragma unroll
                    for (int r = 0; r < 4; r++) {
                        int hp = 16 + r;
                        float fn = bf2f(scw[scoff(c, 40 + hp)]);
                        float z = sigm(g1[1][ct][r]);
                        float hpre = g1[5][ct][r] + hu[1][ct][r];
                        float hv = 2.f / (1.f + __expf(-2.f * hpre)) - 1.f;
                        u16 w = f2bf((1.f - z) * fn + z * hv);
                        nodes[nbase + (size_t)hp * N_SZ] = w;
                        scw[scoff(c, hp)] = w;
                    }
                }
            }

            // 3f: og = Wo1_pad(32x32) @ fn_new
            f4 og[2][2];
            og[0][0] = (f4){0,0,0,0}; og[0][1] = (f4){0,0,0,0};
            og[1][0] = (f4){0,0,0,0}; og[1][1] = (f4){0,0,0,0};
            #pragma unroll
            for (int ct = 0; ct < 2; ct++) {
                int c = ct * 16 + l16;
                int fb = quad ^ (c & 7);
                bf8 bfr = *(const bf8*)&scw[c * 64 + fb * 8];
                #pragma unroll
                for (int mt = 0; mt < 2; mt++) {
                    bf8 wf = *(const bf8*)(wo1 + ((size_t)(mt * 64) + lane) * 8);
                    og[mt][ct] = MFMA(wf, bfr, og[mt][ct]);
                }
            }

            // 3g: out = og + xo, float4 stores
            #pragma unroll
            for (int ct = 0; ct < 2; ct++) {
                int bg = b0 + ct;
                size_t xob = ((size_t)bg * N_SZ + nglob) * H_SZ;
                size_t ob = (((size_t)t_step * B_SZ + bg) * N_SZ + nglob) * H_SZ;
                {
                    f4 v;
                    #pragma unroll
                    for (int r = 0; r < 4; r++) v[r] = og[0][ct][r] + bf2f(xo[xob + quad * 4 + r]);
                    *(f4*)(out + ob + quad * 4) = v;
                }
                if (quad == 0) {
                    f4 v;
                    #pragma unroll
                    for (int r = 0; r < 4; r++) v[r] = og[1][ct][r] + bf2f(xo[xob + 16 + r]);
                    *(f4*)(out + ob + 16) = v;
                }
            }
        }
    }
}

// ---------------- host ----------------
#define WS_NODES   0
#define WS_XO      41943040UL
#define WS_PAT     83886080UL
#define WS_PA      84410368UL
#define WS_WBIG    84934656UL
#define WS_WHU     84946944UL
#define WS_WO1     84948992UL
#define WS_NEEDED  84951040UL

extern "C" void kernel_launch(void* const* d_in, const int* in_sizes, int n_in,
                              void* d_out, int out_size, void* d_ws, size_t ws_size,
                              hipStream_t stream) {
    const float* x    = (const float*)d_in[0];
    const float* A    = (const float*)d_in[1];
    const float* W3w  = (const float*)d_in[2];
    const float* W3u  = (const float*)d_in[3];
    const float* W4w  = (const float*)d_in[4];
    const float* W4u  = (const float*)d_in[5];
    const float* W5w  = (const float*)d_in[6];
    const float* W5u  = (const float*)d_in[7];
    const float* Wout = (const float*)d_in[8];
    const float* bout = (const float*)d_in[9];
    float* out = (float*)d_out;

    if (ws_size < WS_NEEDED) {           // unambiguous failure signature
        ws_too_small<<<1, 1, 0, stream>>>(out);
        return;
    }
    char* ws = (char*)d_ws;
    u16* nodes = (u16*)(ws + WS_NODES);
    u16* xo    = (u16*)(ws + WS_XO);
    u16* pAT   = (u16*)(ws + WS_PAT);
    u16* pA    = (u16*)(ws + WS_PA);
    u16* wbig  = (u16*)(ws + WS_WBIG);
    u16* whu   = (u16*)(ws + WS_WHU);
    u16* wo1   = (u16*)(ws + WS_WO1);

    prep_nodes<<<B_SZ, 256, 0, stream>>>(x, nodes);
    prep_xo<<<(B_SZ * N_SZ) / 256, 256, 0, stream>>>(x, Wout, bout, xo);
    prep_afrag<<<128, 256, 0, stream>>>(A, pAT, pA);
    prep_wfrag<<<4, 256, 0, stream>>>(W3w, W3u, W4w, W4u, W5w, W5u, Wout, wbig, whu, wo1);

    for (int t = 0; t < T_STEPS; t++)
        step_kernel<<<B_SZ / 2, 256, 0, stream>>>(pAT, pA, wbig, whu, wo1, xo, nodes, out, t);
}